// Round 4
// baseline (120.074 us; speedup 1.0000x reference)
//
#include <hip/hip_runtime.h>
#include <hip/hip_fp16.h>

// NNUE forward, R4: split pipeline.
//   convert_ftw : ft_w f32 -> fp16 table in ws            (~9us, HBM-bound)
//   ft_gather   : sparse gather+accum+crelu -> x f32 in ws (no LDS, no sync,
//                 2 boards/wave, scalar indices, max occupancy)
//   mlp_tail    : fc1/fc2/fc3 all f32; weights via wave-uniform s_load
//                 (scalar cache), h1/h2 via padded LDS.
// Rationale: R3 fused kernel spent ~half its memory-pipe budget streaming
// fc1_w through L1 per wave (256 vmem insts/wave vs 64 for the gather).

constexpr int BATCH   = 16384;
constexpr int NNZPB   = 32;
constexpr int NNZ     = BATCH * NNZPB;
constexpr int HIDDEN  = 256;
constexpr int FEATSZ  = 64 * 64 * 10;                       // 40960
constexpr size_t FTW16_BYTES = (size_t)FEATSZ * HIDDEN * 2; // 20,971,520
constexpr size_t X_BYTES     = (size_t)BATCH * 512 * 4;     // 33,554,432

__device__ __forceinline__ float crelu1(float v) {
    return fminf(fmaxf(v, 0.0f), 1.0f);
}

__device__ __forceinline__ float4 crelu4(float4 a) {
    float4 c;
    c.x = crelu1(a.x); c.y = crelu1(a.y);
    c.z = crelu1(a.z); c.w = crelu1(a.w);
    return c;
}

// ---- f32 -> fp16 table conversion -------------------------------------
__global__ __launch_bounds__(256) void convert_ftw(
    const float4* __restrict__ src,
    uint2*        __restrict__ dst,
    int n4)
{
    int i = blockIdx.x * 256 + threadIdx.x;
    const int stride = gridDim.x * 256;
    for (; i < n4; i += stride) {
        const float4 v = src[i];
        const __half2 lo = __floats2half2_rn(v.x, v.y);
        const __half2 hi = __floats2half2_rn(v.z, v.w);
        uint2 o;
        o.x = *reinterpret_cast<const unsigned*>(&lo);
        o.y = *reinterpret_cast<const unsigned*>(&hi);
        dst[i] = o;
    }
}

// half2x2 * scalar f32, f32 accumulate (v_fma_mix)
__device__ __forceinline__ void fma4_fp16(const uint2 r, float v, float4& acc) {
    const __half2 h0 = *reinterpret_cast<const __half2*>(&r.x);
    const __half2 h1 = *reinterpret_cast<const __half2*>(&r.y);
    const float2 f0 = __half22float2(h0);
    const float2 f1 = __half22float2(h1);
    acc.x = fmaf(f0.x, v, acc.x);
    acc.y = fmaf(f0.y, v, acc.y);
    acc.z = fmaf(f1.x, v, acc.z);
    acc.w = fmaf(f1.y, v, acc.w);
}

// ---- kernel 1: pure feature-transform gather --------------------------
// 256 threads = 4 waves; each wave owns 2 boards (4 gather streams).
// x row layout: [board][512] f32 = [board][128] float4; white half first.
__global__ __launch_bounds__(256) void ft_gather(
    const int*    __restrict__ wfeat,
    const float*  __restrict__ wval,
    const int*    __restrict__ bfeat,
    const float*  __restrict__ bval,
    const uint2*  __restrict__ ftw16,
    const float4* __restrict__ ftb,
    float4*       __restrict__ xout)   // [BATCH][128]
{
    const int tid  = threadIdx.x;
    const int w    = tid >> 6;
    const int lane = tid & 63;
    const int b0 = __builtin_amdgcn_readfirstlane((int)(blockIdx.x * 8) + w * 2);
    const int b1 = b0 + 1;

    const int*   wip0 = wfeat + b0 * NNZPB;
    const float* wvp0 = wval  + b0 * NNZPB;
    const int*   bip0 = bfeat + b0 * NNZPB;
    const float* bvp0 = bval  + b0 * NNZPB;
    const int*   wip1 = wfeat + b1 * NNZPB;
    const float* wvp1 = wval  + b1 * NNZPB;
    const int*   bip1 = bfeat + b1 * NNZPB;
    const float* bvp1 = bval  + b1 * NNZPB;

    const float4 bias = ftb[lane];
    float4 aw0 = bias, ab0 = bias, aw1 = bias, ab1 = bias;

    #pragma unroll
    for (int k = 0; k < NNZPB; ++k) {
        const int   fw0 = wip0[k];   // wave-uniform -> s_load
        const float vw0 = wvp0[k];
        const int   fb0 = bip0[k];
        const float vb0 = bvp0[k];
        const int   fw1 = wip1[k];
        const float vw1 = wvp1[k];
        const int   fb1 = bip1[k];
        const float vb1 = bvp1[k];
        const uint2 rw0 = ftw16[fw0 * 64 + lane];
        const uint2 rb0 = ftw16[fb0 * 64 + lane];
        const uint2 rw1 = ftw16[fw1 * 64 + lane];
        const uint2 rb1 = ftw16[fb1 * 64 + lane];
        fma4_fp16(rw0, vw0, aw0);
        fma4_fp16(rb0, vb0, ab0);
        fma4_fp16(rw1, vw1, aw1);
        fma4_fp16(rb1, vb1, ab1);
    }

    xout[b0 * 128 +      lane] = crelu4(aw0);
    xout[b0 * 128 + 64 + lane] = crelu4(ab0);
    xout[b1 * 128 +      lane] = crelu4(aw1);
    xout[b1 * 128 + 64 + lane] = crelu4(ab1);
}

// ---- kernel 2: dense MLP tail, all f32 --------------------------------
// 256 blocks x 256 threads; block handles 64 boards. Thread = (board b_sub,
// output-quarter oq): fc1 acc[8] over 512 inputs; weights wave-uniform ->
// scalar cache. h1/h2 via LDS padded to 33 (conflict-free: 33*l % 32 = l).
__global__ __launch_bounds__(256) void mlp_tail(
    const float4* __restrict__ x4,     // [BATCH][128]
    const float*  __restrict__ fc1w,   // [512][32]
    const float*  __restrict__ fc1b,
    const float*  __restrict__ fc2w,   // [32][32]
    const float*  __restrict__ fc2b,
    const float*  __restrict__ fc3w,   // [32]
    const float*  __restrict__ fc3b,
    float*        __restrict__ out)
{
    __shared__ float h1[64][33];
    __shared__ float h2[64][33];

    const int t     = threadIdx.x;
    const int b_sub = t & 63;
    const int oq    = __builtin_amdgcn_readfirstlane((t >> 6) & 3); // wave id
    const int board = (int)blockIdx.x * 64 + b_sub;

    // fc1: 8 outputs per thread, 512-long dot each
    float acc[8];
    #pragma unroll
    for (int r = 0; r < 8; ++r) acc[r] = fc1b[oq * 8 + r];

    const float4* xr = x4 + (size_t)board * 128;
    #pragma unroll 4
    for (int i4 = 0; i4 < 128; ++i4) {
        const float4 xv = xr[i4];
        const float xs[4] = {xv.x, xv.y, xv.z, xv.w};
        #pragma unroll
        for (int j = 0; j < 4; ++j) {
            const int i = i4 * 4 + j;
            #pragma unroll
            for (int r = 0; r < 8; ++r)
                acc[r] = fmaf(xs[j], fc1w[i * 32 + oq * 8 + r], acc[r]);
        }
    }
    #pragma unroll
    for (int r = 0; r < 8; ++r)
        h1[b_sub][oq * 8 + r] = crelu1(acc[r]);
    __syncthreads();

    // fc2: same mapping
    float a2[8];
    #pragma unroll
    for (int r = 0; r < 8; ++r) a2[r] = fc2b[oq * 8 + r];
    #pragma unroll
    for (int i = 0; i < 32; ++i) {
        const float hv = h1[b_sub][i];
        #pragma unroll
        for (int r = 0; r < 8; ++r)
            a2[r] = fmaf(hv, fc2w[i * 32 + oq * 8 + r], a2[r]);
    }
    #pragma unroll
    for (int r = 0; r < 8; ++r)
        h2[b_sub][oq * 8 + r] = crelu1(a2[r]);
    __syncthreads();

    // fc3
    if (t < 64) {
        float s = fc3b[0];
        #pragma unroll
        for (int i = 0; i < 32; ++i)
            s = fmaf(h2[b_sub][i], fc3w[i], s);
        out[board] = s;
    }
}

// ---- fallback: R3 fused fp16 kernel (if ws too small for x buffer) ----
__global__ __launch_bounds__(256) void nnue_fwd_fp16(
    const int*    __restrict__ wfeat,
    const float*  __restrict__ wval,
    const int*    __restrict__ bfeat,
    const float*  __restrict__ bval,
    const uint2*  __restrict__ ftw16,
    const float4* __restrict__ ftb,
    const float*  __restrict__ fc1w,
    const float*  __restrict__ fc1b,
    const float*  __restrict__ fc2w,
    const float*  __restrict__ fc2b,
    const float*  __restrict__ fc3w,
    const float*  __restrict__ fc3b,
    float*        __restrict__ out)
{
    __shared__ float x[4][2 * HIDDEN];
    __shared__ float p1[4][2][32];
    __shared__ float h1[4][32];
    __shared__ float h2[4][32];

    const int tid  = threadIdx.x;
    const int w    = tid >> 6;
    const int lane = tid & 63;
    const int board = __builtin_amdgcn_readfirstlane((int)(blockIdx.x << 2) + w);

    const int*   wip = wfeat + board * NNZPB;
    const float* wvp = wval  + board * NNZPB;
    const int*   bip = bfeat + board * NNZPB;
    const float* bvp = bval  + board * NNZPB;

    float4 accw = ftb[lane];
    float4 accb = accw;

    #pragma unroll
    for (int k = 0; k < NNZPB; ++k) {
        const int   fw = wip[k];
        const float vw = wvp[k];
        const int   fb = bip[k];
        const float vb = bvp[k];
        const uint2 rw = ftw16[fw * 64 + lane];
        const uint2 rb = ftw16[fb * 64 + lane];
        fma4_fp16(rw, vw, accw);
        fma4_fp16(rb, vb, accb);
    }

    reinterpret_cast<float4*>(x[w])[lane]      = crelu4(accw);
    reinterpret_cast<float4*>(x[w])[64 + lane] = crelu4(accb);
    __syncthreads();

    {
        const int o = lane & 31;
        const int h = lane >> 5;
        const float4* xr = reinterpret_cast<const float4*>(&x[w][h * HIDDEN]);
        const float*  wr = fc1w + (h * HIDDEN) * 32 + o;
        float s = 0.0f;
        #pragma unroll 16
        for (int i4 = 0; i4 < HIDDEN / 4; ++i4) {
            const float4 xv = xr[i4];
            s = fmaf(xv.x, wr[(i4 * 4 + 0) * 32], s);
            s = fmaf(xv.y, wr[(i4 * 4 + 1) * 32], s);
            s = fmaf(xv.z, wr[(i4 * 4 + 2) * 32], s);
            s = fmaf(xv.w, wr[(i4 * 4 + 3) * 32], s);
        }
        p1[w][h][o] = s;
    }
    __syncthreads();

    if (lane < 32) {
        const float v = p1[w][0][lane] + p1[w][1][lane] + fc1b[lane];
        h1[w][lane] = crelu1(v);
    }
    __syncthreads();

    if (lane < 32) {
        float s = fc2b[lane];
        #pragma unroll
        for (int i = 0; i < 32; ++i)
            s = fmaf(h1[w][i], fc2w[i * 32 + lane], s);
        h2[w][lane] = crelu1(s);
    }
    __syncthreads();

    if (lane == 0) {
        float s = fc3b[0];
        #pragma unroll
        for (int i = 0; i < 32; ++i)
            s = fmaf(h2[w][i], fc3w[i], s);
        out[board] = s;
    }
}

extern "C" void kernel_launch(void* const* d_in, const int* in_sizes, int n_in,
                              void* d_out, int out_size, void* d_ws, size_t ws_size,
                              hipStream_t stream) {
    const int*   w_indices = (const int*)  d_in[0];
    const float* w_values  = (const float*)d_in[1];
    const int*   b_indices = (const int*)  d_in[2];
    const float* b_values  = (const float*)d_in[3];
    const float* ft_w      = (const float*)d_in[4];
    const float* ft_b      = (const float*)d_in[5];
    const float* fc1_w     = (const float*)d_in[6];
    const float* fc1_b     = (const float*)d_in[7];
    const float* fc2_w     = (const float*)d_in[8];
    const float* fc2_b     = (const float*)d_in[9];
    const float* fc3_w     = (const float*)d_in[10];
    const float* fc3_b     = (const float*)d_in[11];
    float* out = (float*)d_out;

    const int* wfeat = w_indices + NNZ;
    const int* bfeat = b_indices + NNZ;

    if (ws_size >= FTW16_BYTES + X_BYTES) {
        uint2*  ftw16 = (uint2*)d_ws;
        float4* x4    = (float4*)((char*)d_ws + FTW16_BYTES);
        const int n4 = FEATSZ * HIDDEN / 4;
        convert_ftw<<<2048, 256, 0, stream>>>((const float4*)ft_w, ftw16, n4);
        ft_gather<<<BATCH / 8, 256, 0, stream>>>(
            wfeat, w_values, bfeat, b_values,
            ftw16, (const float4*)ft_b, x4);
        mlp_tail<<<BATCH / 64, 256, 0, stream>>>(
            (const float4*)x4,
            fc1_w, fc1_b, fc2_w, fc2_b, fc3_w, fc3_b, out);
    } else if (ws_size >= FTW16_BYTES) {
        uint2* ftw16 = (uint2*)d_ws;
        const int n4 = FEATSZ * HIDDEN / 4;
        convert_ftw<<<2048, 256, 0, stream>>>((const float4*)ft_w, ftw16, n4);
        nnue_fwd_fp16<<<BATCH / 4, 256, 0, stream>>>(
            wfeat, w_values, bfeat, b_values,
            ftw16, (const float4*)ft_b,
            fc1_w, fc1_b, fc2_w, fc2_b, fc3_w, fc3_b, out);
    }
}

// Round 5
// 120.049 us; speedup vs baseline: 1.0002x; 1.0002x over previous
//
#include <hip/hip_runtime.h>
#include <hip/hip_fp16.h>

// NNUE forward, R5: XCD-sliced L2-resident gather.
//   convert_reorg   : ft_w f32 [40960][256] -> fp16 slice-major [8][40960][32]
//   ft_gather_sliced: slice = blockIdx%8 -> each XCD's L2 holds only its
//                     2.6 MB table slice (fits 4 MB L2). Wave = 8 boards,
//                     lane (g,c) accumulates 4 cols of board g. Writes x
//                     TRANSPOSED (xT[512][16384], nontemporal).
//   mlp_tail_T      : lane = board (coalesced xT reads), fc1 weights via
//                     wave-uniform s_load, acc[32] in VGPRs, LDS reduce,
//                     fc2/fc3 in wave 0.
// Rationale: R4 showed the gather pinned at ~70us with FETCH~0 (L3-resident
// table) -> bound by L2-miss/L3 service, not HBM. Slicing makes it L2-hit.

constexpr int BATCH  = 16384;
constexpr int NNZPB  = 32;
constexpr int NNZ    = BATCH * NNZPB;
constexpr int HIDDEN = 256;
constexpr int FEATSZ = 64 * 64 * 10;          // 40960
constexpr int NSLICE = 8;
constexpr int SCOLS  = HIDDEN / NSLICE;       // 32 cols per slice
constexpr size_t FTW16S_BYTES = (size_t)FEATSZ * HIDDEN * 2;  // 20,971,520
constexpr size_t XT_BYTES     = (size_t)2 * HIDDEN * BATCH * 4; // 33,554,432

__device__ __forceinline__ float crelu1(float v) {
    return fminf(fmaxf(v, 0.0f), 1.0f);
}

// half2x2 * scalar f32, f32 accumulate (v_fma_mix)
__device__ __forceinline__ void fma4_fp16(const uint2 r, float v, float4& acc) {
    const __half2 h0 = *reinterpret_cast<const __half2*>(&r.x);
    const __half2 h1 = *reinterpret_cast<const __half2*>(&r.y);
    const float2 f0 = __half22float2(h0);
    const float2 f1 = __half22float2(h1);
    acc.x = fmaf(f0.x, v, acc.x);
    acc.y = fmaf(f0.y, v, acc.y);
    acc.z = fmaf(f1.x, v, acc.z);
    acc.w = fmaf(f1.y, v, acc.w);
}

// ---- f32 [40960][256] -> fp16 slice-major [8][40960][32] ----------------
__global__ __launch_bounds__(256) void convert_reorg(
    const float4* __restrict__ src,   // ft_w as float4
    uint2*        __restrict__ dst,   // 4 halfs per elem, slice-major linear
    int n)                            // FEATSZ*HIDDEN/4
{
    int i = blockIdx.x * 256 + threadIdx.x;
    const int stride = gridDim.x * 256;
    for (; i < n; i += stride) {
        const int h0 = i * 4;                       // output half index
        const int s  = h0 / (FEATSZ * SCOLS);
        const int r  = h0 - s * (FEATSZ * SCOLS);
        const int f  = r >> 5;                      // feature row
        const int cc = r & 31;                      // col within slice
        const float4 v = src[(f * HIDDEN + s * SCOLS + cc) >> 2];
        const __half2 lo = __floats2half2_rn(v.x, v.y);
        const __half2 hi = __floats2half2_rn(v.z, v.w);
        uint2 o;
        o.x = *reinterpret_cast<const unsigned*>(&lo);
        o.y = *reinterpret_cast<const unsigned*>(&hi);
        dst[i] = o;
    }
}

// ---- sliced gather ------------------------------------------------------
// grid = 8 slices x 512 board-blocks; block = 256 thr = 4 waves; wave = 8
// boards. lane = (g = board-sub, c = col-chunk). Per feature: group g reads
// 8 B (4 halfs) of its board's row-slice. Output transposed + nontemporal.
__global__ __launch_bounds__(256) void ft_gather_sliced(
    const int*   __restrict__ wfeat,
    const float* __restrict__ wval,
    const int*   __restrict__ bfeat,
    const float* __restrict__ bval,
    const uint2* __restrict__ ftw16s,  // [8][40960][8] uint2
    const float* __restrict__ ftb,     // [256]
    float*       __restrict__ xT)      // [512][16384]
{
    const int s    = blockIdx.x & 7;          // slice -> XCD via round-robin
    const int bb   = blockIdx.x >> 3;
    const int tid  = threadIdx.x;
    const int w    = tid >> 6;
    const int lane = tid & 63;
    const int g    = lane >> 3;               // board sub-index 0..7
    const int c    = lane & 7;                // col chunk 0..7 (4 halfs each)
    const int board = bb * 32 + w * 8 + g;

    const uint2* tb = ftw16s + (size_t)s * FEATSZ * 8;
    const int*   wip = wfeat + board * NNZPB;
    const float* wvp = wval  + board * NNZPB;
    const int*   bip = bfeat + board * NNZPB;
    const float* bvp = bval  + board * NNZPB;

    float4 aw = {0.f, 0.f, 0.f, 0.f};
    float4 ab = {0.f, 0.f, 0.f, 0.f};

    #pragma unroll
    for (int b4 = 0; b4 < NNZPB / 4; ++b4) {
        const int4   wi = *reinterpret_cast<const int4*>  (wip + b4 * 4);
        const float4 wv = *reinterpret_cast<const float4*>(wvp + b4 * 4);
        const int4   bi = *reinterpret_cast<const int4*>  (bip + b4 * 4);
        const float4 bv = *reinterpret_cast<const float4*>(bvp + b4 * 4);
        fma4_fp16(tb[wi.x * 8 + c], wv.x, aw);
        fma4_fp16(tb[bi.x * 8 + c], bv.x, ab);
        fma4_fp16(tb[wi.y * 8 + c], wv.y, aw);
        fma4_fp16(tb[bi.y * 8 + c], bv.y, ab);
        fma4_fp16(tb[wi.z * 8 + c], wv.z, aw);
        fma4_fp16(tb[bi.z * 8 + c], bv.z, ab);
        fma4_fp16(tb[wi.w * 8 + c], wv.w, aw);
        fma4_fp16(tb[bi.w * 8 + c], bv.w, ab);
    }

    const int colW = s * SCOLS + c * 4;       // white col base; black = +256
    const float4 bias = *reinterpret_cast<const float4*>(ftb + colW);

    float* pw = xT + (size_t)colW * BATCH + board;
    float* pb = xT + (size_t)(HIDDEN + colW) * BATCH + board;
    __builtin_nontemporal_store(crelu1(aw.x + bias.x), pw);
    __builtin_nontemporal_store(crelu1(aw.y + bias.y), pw + BATCH);
    __builtin_nontemporal_store(crelu1(aw.z + bias.z), pw + 2 * BATCH);
    __builtin_nontemporal_store(crelu1(aw.w + bias.w), pw + 3 * BATCH);
    __builtin_nontemporal_store(crelu1(ab.x + bias.x), pb);
    __builtin_nontemporal_store(crelu1(ab.y + bias.y), pb + BATCH);
    __builtin_nontemporal_store(crelu1(ab.z + bias.z), pb + 2 * BATCH);
    __builtin_nontemporal_store(crelu1(ab.w + bias.w), pb + 3 * BATCH);
}

// ---- MLP tail on transposed x ------------------------------------------
// 256 blocks x 256 thr; wave = input-quarter (uniform), lane = board.
// fc1 weights wave-uniform -> s_load, broadcast to all 64 lanes.
__global__ __launch_bounds__(256) void mlp_tail_T(
    const float* __restrict__ xT,      // [512][16384]
    const float* __restrict__ fc1w,    // [512][32]
    const float* __restrict__ fc1b,
    const float* __restrict__ fc2w,    // [32][32]
    const float* __restrict__ fc2b,
    const float* __restrict__ fc3w,    // [32]
    const float* __restrict__ fc3b,
    float*       __restrict__ out)
{
    __shared__ float red[3][64][33];   // +1 pad: conflict-free

    const int tid  = threadIdx.x;
    const int iq   = __builtin_amdgcn_readfirstlane(tid >> 6);
    const int lane = tid & 63;
    const int board = (int)blockIdx.x * 64 + lane;

    float acc[32];
    #pragma unroll
    for (int o = 0; o < 32; ++o) acc[o] = 0.0f;

    const float* xp = xT + (size_t)(iq * 128) * BATCH + board;
    const float* wp = fc1w + iq * 128 * 32;
    #pragma unroll 4
    for (int i = 0; i < 128; ++i) {
        const float xv = __builtin_nontemporal_load(xp + (size_t)i * BATCH);
        const float* wr = wp + i * 32;           // wave-uniform -> s_load
        #pragma unroll
        for (int o = 0; o < 32; ++o)
            acc[o] = fmaf(xv, wr[o], acc[o]);
    }

    if (iq > 0) {
        #pragma unroll
        for (int o = 0; o < 32; ++o)
            red[iq - 1][lane][o] = acc[o];
    }
    __syncthreads();

    if (iq == 0) {
        #pragma unroll
        for (int o = 0; o < 32; ++o)
            acc[o] = crelu1(acc[o] + red[0][lane][o] + red[1][lane][o] +
                            red[2][lane][o] + fc1b[o]);
        float a2[32];
        #pragma unroll
        for (int o = 0; o < 32; ++o) a2[o] = fc2b[o];
        #pragma unroll
        for (int i = 0; i < 32; ++i) {
            const float hv = acc[i];
            #pragma unroll
            for (int o = 0; o < 32; ++o)
                a2[o] = fmaf(hv, fc2w[i * 32 + o], a2[o]);
        }
        float sum = fc3b[0];
        #pragma unroll
        for (int i = 0; i < 32; ++i)
            sum = fmaf(crelu1(a2[i]), fc3w[i], sum);
        out[board] = sum;
    }
}

// ---- fallback: R3 fused fp16 kernel (needs only the 21 MB table) -------
__global__ __launch_bounds__(256) void nnue_fwd_fp16(
    const int*   __restrict__ wfeat,
    const float* __restrict__ wval,
    const int*   __restrict__ bfeat,
    const float* __restrict__ bval,
    const uint2* __restrict__ ftw16,   // plain row-major [40960][32] uint2
    const float4* __restrict__ ftb,
    const float* __restrict__ fc1w,
    const float* __restrict__ fc1b,
    const float* __restrict__ fc2w,
    const float* __restrict__ fc2b,
    const float* __restrict__ fc3w,
    const float* __restrict__ fc3b,
    float*       __restrict__ out)
{
    __shared__ float x[4][2 * HIDDEN];
    __shared__ float p1[4][2][32];
    __shared__ float h1[4][32];
    __shared__ float h2[4][32];

    const int tid  = threadIdx.x;
    const int w    = tid >> 6;
    const int lane = tid & 63;
    const int board = __builtin_amdgcn_readfirstlane((int)(blockIdx.x << 2) + w);

    const int*   wip = wfeat + board * NNZPB;
    const float* wvp = wval  + board * NNZPB;
    const int*   bip = bfeat + board * NNZPB;
    const float* bvp = bval  + board * NNZPB;

    float4 accw = ftb[lane];
    float4 accb = accw;

    #pragma unroll
    for (int k = 0; k < NNZPB; ++k) {
        const int   fw = wip[k];
        const float vw = wvp[k];
        const int   fb = bip[k];
        const float vb = bvp[k];
        const uint2 rw = ftw16[fw * 64 + lane];
        const uint2 rb = ftw16[fb * 64 + lane];
        fma4_fp16(rw, vw, accw);
        fma4_fp16(rb, vb, accb);
    }

    {
        float4 cw, cb;
        cw.x = crelu1(accw.x); cw.y = crelu1(accw.y);
        cw.z = crelu1(accw.z); cw.w = crelu1(accw.w);
        cb.x = crelu1(accb.x); cb.y = crelu1(accb.y);
        cb.z = crelu1(accb.z); cb.w = crelu1(accb.w);
        reinterpret_cast<float4*>(x[w])[lane]      = cw;
        reinterpret_cast<float4*>(x[w])[64 + lane] = cb;
    }
    __syncthreads();

    {
        const int o = lane & 31;
        const int h = lane >> 5;
        const float4* xr = reinterpret_cast<const float4*>(&x[w][h * HIDDEN]);
        const float*  wr = fc1w + (h * HIDDEN) * 32 + o;
        float s = 0.0f;
        #pragma unroll 16
        for (int i4 = 0; i4 < HIDDEN / 4; ++i4) {
            const float4 xv = xr[i4];
            s = fmaf(xv.x, wr[(i4 * 4 + 0) * 32], s);
            s = fmaf(xv.y, wr[(i4 * 4 + 1) * 32], s);
            s = fmaf(xv.z, wr[(i4 * 4 + 2) * 32], s);
            s = fmaf(xv.w, wr[(i4 * 4 + 3) * 32], s);
        }
        p1[w][h][o] = s;
    }
    __syncthreads();

    if (lane < 32) {
        const float v = p1[w][0][lane] + p1[w][1][lane] + fc1b[lane];
        h1[w][lane] = crelu1(v);
    }
    __syncthreads();

    if (lane < 32) {
        float s = fc2b[lane];
        #pragma unroll
        for (int i = 0; i < 32; ++i)
            s = fmaf(h1[w][i], fc2w[i * 32 + lane], s);
        h2[w][lane] = crelu1(s);
    }
    __syncthreads();

    if (lane == 0) {
        float s = fc3b[0];
        #pragma unroll
        for (int i = 0; i < 32; ++i)
            s = fmaf(h2[w][i], fc3w[i], s);
        out[board] = s;
    }
}

__global__ __launch_bounds__(256) void convert_ftw_plain(
    const float4* __restrict__ src,
    uint2*        __restrict__ dst,
    int n4)
{
    int i = blockIdx.x * 256 + threadIdx.x;
    const int stride = gridDim.x * 256;
    for (; i < n4; i += stride) {
        const float4 v = src[i];
        const __half2 lo = __floats2half2_rn(v.x, v.y);
        const __half2 hi = __floats2half2_rn(v.z, v.w);
        uint2 o;
        o.x = *reinterpret_cast<const unsigned*>(&lo);
        o.y = *reinterpret_cast<const unsigned*>(&hi);
        dst[i] = o;
    }
}

extern "C" void kernel_launch(void* const* d_in, const int* in_sizes, int n_in,
                              void* d_out, int out_size, void* d_ws, size_t ws_size,
                              hipStream_t stream) {
    const int*   w_indices = (const int*)  d_in[0];
    const float* w_values  = (const float*)d_in[1];
    const int*   b_indices = (const int*)  d_in[2];
    const float* b_values  = (const float*)d_in[3];
    const float* ft_w      = (const float*)d_in[4];
    const float* ft_b      = (const float*)d_in[5];
    const float* fc1_w     = (const float*)d_in[6];
    const float* fc1_b     = (const float*)d_in[7];
    const float* fc2_w     = (const float*)d_in[8];
    const float* fc2_b     = (const float*)d_in[9];
    const float* fc3_w     = (const float*)d_in[10];
    const float* fc3_b     = (const float*)d_in[11];
    float* out = (float*)d_out;

    const int* wfeat = w_indices + NNZ;
    const int* bfeat = b_indices + NNZ;

    if (ws_size >= FTW16S_BYTES + XT_BYTES) {
        uint2* ftw16s = (uint2*)d_ws;
        float* xT     = (float*)((char*)d_ws + FTW16S_BYTES);
        convert_reorg<<<4096, 256, 0, stream>>>(
            (const float4*)ft_w, ftw16s, FEATSZ * HIDDEN / 4);
        ft_gather_sliced<<<NSLICE * (BATCH / 32), 256, 0, stream>>>(
            wfeat, w_values, bfeat, b_values, ftw16s, ft_b, xT);
        mlp_tail_T<<<BATCH / 64, 256, 0, stream>>>(
            xT, fc1_w, fc1_b, fc2_w, fc2_b, fc3_w, fc3_b, out);
    } else if (ws_size >= FTW16S_BYTES) {
        uint2* ftw16 = (uint2*)d_ws;
        convert_ftw_plain<<<2048, 256, 0, stream>>>(
            (const float4*)ft_w, ftw16, FEATSZ * HIDDEN / 4);
        nnue_fwd_fp16<<<BATCH / 4, 256, 0, stream>>>(
            wfeat, w_values, bfeat, b_values,
            ftw16, (const float4*)ft_b,
            fc1_w, fc1_b, fc2_w, fc2_b, fc3_w, fc3_b, out);
    }
}